// Round 1
// baseline (83530.957 us; speedup 1.0000x reference)
//
#include <hip/hip_runtime.h>
#include <hip/hip_bf16.h>

// LSTM_19267223290530 — 2-layer LSTM (B=64,T=1024,IN=128,HID=512) + FC.
// Round 0: correct fp32 baseline with persistent scan kernels + group barriers.

#define NTH 256
#define WPG 64      // workgroups per barrier group
#define NGRP 4      // batch groups
#define BPG 16      // batches per group
#define UPW 8       // hidden units per wg
#define RPW 32      // gate rows per wg (4*UPW)
#define HIDDEN 512
#define TSTEPS 1024
#define BATCH 64

using bf16 = __hip_bfloat16;

__device__ __forceinline__ float b2fl(unsigned short s) {
  return __uint_as_float(((unsigned int)s) << 16);
}

template<typename T> struct Ld4;
template<> struct Ld4<float> {
  static __device__ __forceinline__ float4 go(const float* p) { return *(const float4*)p; }
};
template<> struct Ld4<bf16> {
  static __device__ __forceinline__ float4 go(const bf16* p) {
    ushort4 v = *(const ushort4*)p;
    return make_float4(b2fl(v.x), b2fl(v.y), b2fl(v.z), b2fl(v.w));
  }
};

template<typename T> __device__ __forceinline__ T to_xout(float f);
template<> __device__ __forceinline__ float to_xout<float>(float f) { return f; }
template<> __device__ __forceinline__ bf16 to_xout<bf16>(float f) { return __float2bfloat16(f); }

__device__ __forceinline__ float sigm(float x) { return 1.0f / (1.0f + __expf(-x)); }
__device__ __forceinline__ float tanh_fast(float x) {
  float ax = fabsf(x);
  float e2 = __expf(2.0f * ax);
  float t  = 1.0f - 2.0f / (e2 + 1.0f);
  return copysignf(t, x);
}
__device__ __forceinline__ void fma4(float& a, const float4 w, const float4 h) {
  a = fmaf(w.x, h.x, a);
  a = fmaf(w.y, h.y, a);
  a = fmaf(w.z, h.z, a);
  a = fmaf(w.w, h.w, a);
}

// ---------------------------------------------------------------------------
// Persistent LSTM scan. grid = 256 wgs x 256 thr, all co-resident.
// group g = bid&3 owns batches [16g,16g+16); wg w = bid>>2 owns units [8w,8w+8).
// Per step: stage h(prev)+x -> LDS, 4x4 reg-blocked dots (K-split 8),
// LDS reduce, gates, write h slice to global double buffer, group barrier.
// ---------------------------------------------------------------------------
template<int D_IN, bool WRITE_SEQ, typename XIN, typename XOUT>
__global__ __launch_bounds__(NTH, 1)
void lstm_scan(const XIN* __restrict__ xin,
               const float* __restrict__ w_ih,
               const float* __restrict__ w_hh,
               const float* __restrict__ b_ih,
               const float* __restrict__ b_hh,
               float* __restrict__ hbuf,        // [2][64][512]
               XOUT* __restrict__ seqout,       // [64][1024][512] (WRITE_SEQ)
               int* __restrict__ barbase)       // 4 groups x 64 ints
{
  constexpr int D4 = D_IN / 4;
  constexpr bool XW_LDS = (D_IN <= 128);        // layer0: w_ih fits LDS
  constexpr int S4 = 128 + (XW_LDS ? D4 : 0);   // wv row stride (float4)
  constexpr int XC = D_IN / 8;                  // x K-chunk per kc
  constexpr int LD4 = (D_IN == 128) ? 5 : 7;

  extern __shared__ float lds[];
  float4* wv4 = (float4*)lds;                   // [RPW][S4] swizzled
  float4* hs4 = wv4 + RPW * S4;                 // [BPG][128] swizzled
  float4* xs4 = hs4 + BPG * 128;                // [BPG][D4]  swizzled
  float*  red = (float*)(xs4 + BPG * D4);       // [8][512]; row0 doubles as gbuf
  float*  bsum = red + 8 * 512;                 // [32]
  float*  cst  = bsum + RPW;                    // [16][8] c-state

  const int tid = threadIdx.x;
  const int bid = blockIdx.x;
  const int g   = bid & 3;
  const int w   = bid >> 2;
  const int b0g = g * BPG;
  const int u0  = w * UPW;
  int* bar = barbase + g * 64;                  // [0]=cnt, [32]=epoch

  // ---- weights -> LDS (XOR swizzle: col4 ^ ((r>>2)&7) spreads bank quads) ----
  for (int idx = tid; idx < RPW * S4; idx += NTH) {
    int r  = idx / S4;
    int c4 = idx - r * S4;
    int swz = (r >> 2) & 7;
    int grow = ((r >> 3) * HIDDEN) + u0 + (r & 7);
    if (c4 < 128) {
      float4 v = *(const float4*)(w_hh + (size_t)grow * HIDDEN + c4 * 4);
      wv4[r * S4 + (c4 ^ swz)] = v;
    } else {
      int c4x = c4 - 128;
      float4 v = *(const float4*)(w_ih + (size_t)grow * D_IN + c4x * 4);
      wv4[r * S4 + 128 + (c4x ^ swz)] = v;
    }
  }
  if (tid < RPW) {
    int grow = ((tid >> 3) * HIDDEN) + u0 + (tid & 7);
    bsum[tid] = b_ih[grow] + b_hh[grow];
  }
  if (tid < UPW * BPG) cst[tid] = 0.0f;

  const int rr = tid & 7;          // row quad
  const int bb = (tid >> 3) & 3;   // batch quad
  const int kc = tid >> 5;         // K chunk 0..7

  const float* wxg[4];             // layer1: x-weight rows stream from L2
  if (!XW_LDS) {
#pragma unroll
    for (int j = 0; j < 4; ++j) {
      int r = 4 * rr + j;
      int grow = ((r >> 3) * HIDDEN) + u0 + (r & 7);
      wxg[j] = w_ih + (size_t)grow * D_IN;
    }
  }
  __syncthreads();

  for (int t = 0; t < TSTEPS; ++t) {
    const float* hsrc = hbuf + (size_t)(t & 1) * (BATCH * HIDDEN);
    float*       hdst = hbuf + (size_t)((t + 1) & 1) * (BATCH * HIDDEN);

    // stage h_prev (16 batches x 512)
#pragma unroll
    for (int n = 0; n < (BPG * 128) / NTH; ++n) {
      int idx = tid + n * NTH;
      int b = idx >> 7, c4 = idx & 127;
      float4 v = *(const float4*)(hsrc + (size_t)(b0g + b) * HIDDEN + c4 * 4);
      hs4[b * 128 + (c4 ^ (b >> 2))] = v;
    }
    // stage x_t
    for (int idx = tid; idx < BPG * D4; idx += NTH) {
      int b = idx >> LD4, c4 = idx & (D4 - 1);
      float4 v = Ld4<XIN>::go(xin + ((size_t)(b0g + b) * TSTEPS + t) * D_IN + c4 * 4);
      xs4[b * D4 + (c4 ^ (b >> 2))] = v;
    }
    __syncthreads();

    float acc[4][4];
#pragma unroll
    for (int j = 0; j < 4; ++j)
#pragma unroll
      for (int i = 0; i < 4; ++i) acc[j][i] = 0.0f;

    // ---- h part: K chunk [kc*64, kc*64+64) ----
#pragma unroll 4
    for (int kk = 0; kk < 16; ++kk) {
      const int k4 = kc * 16 + kk;
      float4 wq[4], hq[4];
#pragma unroll
      for (int j = 0; j < 4; ++j) wq[j] = wv4[(4 * rr + j) * S4 + (k4 ^ rr)];
#pragma unroll
      for (int i = 0; i < 4; ++i) hq[i] = hs4[(4 * bb + i) * 128 + (k4 ^ bb)];
#pragma unroll
      for (int j = 0; j < 4; ++j)
#pragma unroll
        for (int i = 0; i < 4; ++i) fma4(acc[j][i], wq[j], hq[i]);
    }
    // ---- x part ----
#pragma unroll 2
    for (int kk = 0; kk < XC / 4; ++kk) {
      const int k4 = kc * (XC / 4) + kk;
      float4 wq[4], xq[4];
      if constexpr (XW_LDS) {
#pragma unroll
        for (int j = 0; j < 4; ++j) wq[j] = wv4[(4 * rr + j) * S4 + 128 + (k4 ^ rr)];
      } else {
#pragma unroll
        for (int j = 0; j < 4; ++j) wq[j] = *(const float4*)(wxg[j] + k4 * 4);
      }
#pragma unroll
      for (int i = 0; i < 4; ++i) xq[i] = xs4[(4 * bb + i) * D4 + (k4 ^ bb)];
#pragma unroll
      for (int j = 0; j < 4; ++j)
#pragma unroll
        for (int i = 0; i < 4; ++i) fma4(acc[j][i], wq[j], xq[i]);
    }

    // ---- K-split reduction ----
#pragma unroll
    for (int j = 0; j < 4; ++j)
#pragma unroll
      for (int i = 0; i < 4; ++i)
        red[kc * 512 + (4 * rr + j) * 16 + 4 * bb + i] = acc[j][i];
    __syncthreads();
    {
      const int a0 = tid, a1 = tid + 256;
      float s0 = bsum[a0 >> 4], s1 = bsum[a1 >> 4];
#pragma unroll
      for (int k2 = 0; k2 < 8; ++k2) {
        s0 += red[k2 * 512 + a0];
        s1 += red[k2 * 512 + a1];
      }
      red[a0] = s0;   // gbuf alias: only this thread reads/writes column a0/a1
      red[a1] = s1;
    }
    __syncthreads();

    // ---- gates / state update ----
    if (tid < UPW * BPG) {
      const int lu = tid & 7, bl = tid >> 3;
      float gi = red[(0  + lu) * 16 + bl];
      float gf = red[(8  + lu) * 16 + bl];
      float gg = red[(16 + lu) * 16 + bl];
      float go = red[(24 + lu) * 16 + bl];
      float iv = sigm(gi), fv = sigm(gf), gv = tanh_fast(gg), ov = sigm(go);
      float c = fv * cst[tid] + iv * gv;
      cst[tid] = c;
      float hn = ov * tanh_fast(c);
      const int b = b0g + bl, u = u0 + lu;
      hdst[(size_t)b * HIDDEN + u] = hn;
      if constexpr (WRITE_SEQ)
        seqout[((size_t)b * TSTEPS + t) * HIDDEN + u] = to_xout<XOUT>(hn);
    }

    // ---- group barrier (monotone epoch) ----
    __builtin_amdgcn_fence(__ATOMIC_RELEASE, "agent");
    __syncthreads();
    if (tid == 0) {
      const int target = (t + 1) * WPG;
      int prev = __hip_atomic_fetch_add(bar, 1, __ATOMIC_ACQ_REL, __HIP_MEMORY_SCOPE_AGENT);
      if (prev == target - 1) {
        __hip_atomic_store(bar + 32, t + 1, __ATOMIC_RELEASE, __HIP_MEMORY_SCOPE_AGENT);
      } else {
        while (__hip_atomic_load(bar + 32, __ATOMIC_ACQUIRE, __HIP_MEMORY_SCOPE_AGENT) < t + 1)
          __builtin_amdgcn_s_sleep(1);
      }
    }
    __syncthreads();
    __builtin_amdgcn_fence(__ATOMIC_ACQUIRE, "agent");
  }
}

// ---------------------------------------------------------------------------
// FC: out[b][o] = dot(h2[b], fc_w[o]) + fc_b[o].  grid 8, block 256.
// ---------------------------------------------------------------------------
__global__ __launch_bounds__(NTH, 1)
void fc_kernel(const float* __restrict__ h2, const float* __restrict__ fcw,
               const float* __restrict__ fcb, float* __restrict__ out)
{
  extern __shared__ float lds[];
  float4* fw4 = (float4*)lds;          // [64][128] swizzled
  float4* h24 = fw4 + 64 * 128;        // [8][128]
  const int tid = threadIdx.x;
  const int bq  = blockIdx.x;

  for (int idx = tid; idx < 64 * 128; idx += NTH) {
    int o = idx >> 7, c4 = idx & 127;
    fw4[o * 128 + (c4 ^ (o & 7))] = *(const float4*)(fcw + (size_t)o * HIDDEN + c4 * 4);
  }
  for (int idx = tid; idx < 8 * 128; idx += NTH) {
    int b = idx >> 7, c4 = idx & 127;
    h24[b * 128 + c4] = *(const float4*)(h2 + (size_t)(bq * 8 + b) * HIDDEN + c4 * 4);
  }
  __syncthreads();

  const int o = tid & 63, bs = tid >> 6;
  float a0 = 0.f, a1 = 0.f;
  for (int c4 = 0; c4 < 128; ++c4) {
    float4 wv = fw4[o * 128 + (c4 ^ (o & 7))];
    float4 h0 = h24[(2 * bs) * 128 + c4];
    float4 h1 = h24[(2 * bs + 1) * 128 + c4];
    fma4(a0, wv, h0);
    fma4(a1, wv, h1);
  }
  const float bo = fcb[o];
  out[(size_t)(bq * 8 + 2 * bs) * 64 + o]     = a0 + bo;
  out[(size_t)(bq * 8 + 2 * bs + 1) * 64 + o] = a1 + bo;
}

__global__ void init_ws(float* hbuf0, float* hbuf1, int* bars)
{
  int i = blockIdx.x * blockDim.x + threadIdx.x;
  if (i < 2 * BATCH * HIDDEN) { hbuf0[i] = 0.f; hbuf1[i] = 0.f; }
  if (i < 512) bars[i] = 0;
}

// ---------------------------------------------------------------------------
extern "C" void kernel_launch(void* const* d_in, const int* in_sizes, int n_in,
                              void* d_out, int out_size, void* d_ws, size_t ws_size,
                              hipStream_t stream)
{
  const float* x    = (const float*)d_in[0];
  const float* wih0 = (const float*)d_in[1];
  const float* whh0 = (const float*)d_in[2];
  const float* bih0 = (const float*)d_in[3];
  const float* bhh0 = (const float*)d_in[4];
  const float* wih1 = (const float*)d_in[5];
  const float* whh1 = (const float*)d_in[6];
  const float* bih1 = (const float*)d_in[7];
  const float* bhh1 = (const float*)d_in[8];
  const float* fcw  = (const float*)d_in[9];
  const float* fcb  = (const float*)d_in[10];
  float* out = (float*)d_out;

  float* wsf   = (float*)d_ws;
  int*   bars  = (int*)d_ws;                 // 512 ints (L0: 0..255, L1: 256..511)
  float* hbuf0 = wsf + 512;
  float* hbuf1 = hbuf0 + 2 * BATCH * HIDDEN;
  float* seqf  = hbuf1 + 2 * BATCH * HIDDEN;
  const size_t seq_elems = (size_t)BATCH * TSTEPS * HIDDEN;
  const size_t base_bytes = (512 + 4 * BATCH * HIDDEN) * 4;
  const bool f32seq = ws_size >= base_bytes + seq_elems * 4;

  // LDS sizes (bytes)
  const size_t lds0  = (size_t)((RPW * 160 + BPG * 128 + BPG * 32) * 4 + 8 * 512 + RPW + 128) * 4;
  const size_t lds1  = (size_t)((RPW * 128 + BPG * 128 + BPG * 128) * 4 + 8 * 512 + RPW + 128) * 4;
  const size_t ldsfc = (size_t)(64 * 128 + 8 * 128) * 16;

  hipLaunchKernelGGL(init_ws, dim3(256), dim3(256), 0, stream, hbuf0, hbuf1, bars);

  int* bar0 = bars;
  int* bar1 = bars + 256;
  float* dummy = nullptr;

  if (f32seq) {
    auto* k0 = lstm_scan<128, true,  float, float>;
    auto* k1 = lstm_scan<512, false, float, float>;
    hipFuncSetAttribute((const void*)k0, hipFuncAttributeMaxDynamicSharedMemorySize, (int)lds0);
    hipFuncSetAttribute((const void*)k1, hipFuncAttributeMaxDynamicSharedMemorySize, (int)lds1);
    float* seqp = seqf;
    void* a0[] = { (void*)&x,    (void*)&wih0, (void*)&whh0, (void*)&bih0, (void*)&bhh0,
                   (void*)&hbuf0, (void*)&seqp, (void*)&bar0 };
    if (hipLaunchCooperativeKernel((const void*)k0, dim3(NGRP * WPG), dim3(NTH), a0,
                                   (unsigned)lds0, stream) != hipSuccess) {
      lstm_scan<128, true, float, float><<<dim3(NGRP * WPG), dim3(NTH), lds0, stream>>>(
          x, wih0, whh0, bih0, bhh0, hbuf0, seqp, bar0);
    }
    const float* seqc = seqf;
    void* a1[] = { (void*)&seqc, (void*)&wih1, (void*)&whh1, (void*)&bih1, (void*)&bhh1,
                   (void*)&hbuf1, (void*)&dummy, (void*)&bar1 };
    if (hipLaunchCooperativeKernel((const void*)k1, dim3(NGRP * WPG), dim3(NTH), a1,
                                   (unsigned)lds1, stream) != hipSuccess) {
      lstm_scan<512, false, float, float><<<dim3(NGRP * WPG), dim3(NTH), lds1, stream>>>(
          seqc, wih1, whh1, bih1, bhh1, hbuf1, dummy, bar1);
    }
  } else {
    auto* k0 = lstm_scan<128, true,  float, bf16>;
    auto* k1 = lstm_scan<512, false, bf16, float>;
    hipFuncSetAttribute((const void*)k0, hipFuncAttributeMaxDynamicSharedMemorySize, (int)lds0);
    hipFuncSetAttribute((const void*)k1, hipFuncAttributeMaxDynamicSharedMemorySize, (int)lds1);
    bf16* seqb = (bf16*)seqf;
    void* a0[] = { (void*)&x,    (void*)&wih0, (void*)&whh0, (void*)&bih0, (void*)&bhh0,
                   (void*)&hbuf0, (void*)&seqb, (void*)&bar0 };
    if (hipLaunchCooperativeKernel((const void*)k0, dim3(NGRP * WPG), dim3(NTH), a0,
                                   (unsigned)lds0, stream) != hipSuccess) {
      lstm_scan<128, true, float, bf16><<<dim3(NGRP * WPG), dim3(NTH), lds0, stream>>>(
          x, wih0, whh0, bih0, bhh0, hbuf0, seqb, bar0);
    }
    const bf16* seqc = (const bf16*)seqf;
    void* a1[] = { (void*)&seqc, (void*)&wih1, (void*)&whh1, (void*)&bih1, (void*)&bhh1,
                   (void*)&hbuf1, (void*)&dummy, (void*)&bar1 };
    if (hipLaunchCooperativeKernel((const void*)k1, dim3(NGRP * WPG), dim3(NTH), a1,
                                   (unsigned)lds1, stream) != hipSuccess) {
      lstm_scan<512, false, bf16, float><<<dim3(NGRP * WPG), dim3(NTH), lds1, stream>>>(
          seqc, wih1, whh1, bih1, bhh1, hbuf1, dummy, bar1);
    }
  }

  hipFuncSetAttribute((const void*)fc_kernel, hipFuncAttributeMaxDynamicSharedMemorySize, (int)ldsfc);
  hipLaunchKernelGGL(fc_kernel, dim3(8), dim3(NTH), ldsfc, stream, hbuf1, fcw, fcb, out);
}

// Round 4
// 37285.162 us; speedup vs baseline: 2.2403x; 2.2403x over previous
//
#include <hip/hip_runtime.h>
#include <hip/hip_bf16.h>

// LSTM_19267223290530 — 2-layer LSTM (B=64,T=1024,IN=128,HID=512) + FC.
// Round 3: Round-2 kernel + bounded spin (s_memrealtime bail-out) so any
// violated barrier assumption fails the bench instead of wedging the GPU.
// Core change vs Round 1 remains: relaxed agent atomics (no buffer_wbl2/
// buffer_inv cache maintenance) for flag-array barrier + h exchange.

#define NTH 256
#define WPG 64      // workgroups per barrier group
#define NGRP 4      // batch groups
#define BPG 16      // batches per group
#define UPW 8       // hidden units per wg
#define RPW 32      // gate rows per wg (4*UPW)
#define HIDDEN 512
#define TSTEPS 1024
#define BATCH 64

// spin bail-out: s_memrealtime ticks (~100 MHz) -> ~4 s. Never fires unless
// co-residency/coherence assumptions are broken; then we terminate wrong
// rather than hang the container.
#define SPIN_LIMIT 400000000ull

using bf16 = __hip_bfloat16;

__device__ __forceinline__ float b2fl(unsigned short s) {
  return __uint_as_float(((unsigned int)s) << 16);
}

template<typename T> struct Ld4;
template<> struct Ld4<float> {
  static __device__ __forceinline__ float4 go(const float* p) { return *(const float4*)p; }
};
template<> struct Ld4<bf16> {
  static __device__ __forceinline__ float4 go(const bf16* p) {
    ushort4 v = *(const ushort4*)p;
    return make_float4(b2fl(v.x), b2fl(v.y), b2fl(v.z), b2fl(v.w));
  }
};

template<typename T> __device__ __forceinline__ T to_xout(float f);
template<> __device__ __forceinline__ float to_xout<float>(float f) { return f; }
template<> __device__ __forceinline__ bf16 to_xout<bf16>(float f) { return __float2bfloat16(f); }

__device__ __forceinline__ float sigm(float x) { return 1.0f / (1.0f + __expf(-x)); }
__device__ __forceinline__ float tanh_fast(float x) {
  float ax = fabsf(x);
  float e2 = __expf(2.0f * ax);
  float t  = 1.0f - 2.0f / (e2 + 1.0f);
  return copysignf(t, x);
}
__device__ __forceinline__ void fma4(float& a, const float4 w, const float4 h) {
  a = fmaf(w.x, h.x, a);
  a = fmaf(w.y, h.y, a);
  a = fmaf(w.z, h.z, a);
  a = fmaf(w.w, h.w, a);
}

// coherent (device-visible, no cache maintenance) scalar ops
__device__ __forceinline__ void st_cc(float* p, float v) {
  __hip_atomic_store(p, v, __ATOMIC_RELAXED, __HIP_MEMORY_SCOPE_AGENT);
}
__device__ __forceinline__ float ld_cc(const float* p) {
  return __hip_atomic_load((float*)p, __ATOMIC_RELAXED, __HIP_MEMORY_SCOPE_AGENT);
}

// ---------------------------------------------------------------------------
// Persistent LSTM scan. grid = 256 wgs x 256 thr, all co-resident (LDS caps
// residency at 1 wg/CU; 256 wgs <= 256 CUs — co-residency proven by Round 1,
// whose spinning barrier passed on this harness with both launch paths).
// group g = bid&3 owns batches [16g,16g+16); wg w = bid>>2 owns units [8w,8w+8).
// Per step: stage h(prev)+x -> LDS, 4x4 reg-blocked dots (K-split 8),
// LDS reduce, gates, coherent h write, flag-array group barrier (no RMW).
// ---------------------------------------------------------------------------
template<int D_IN, bool WRITE_SEQ, typename XIN, typename XOUT>
__global__ __launch_bounds__(NTH, 1)
void lstm_scan(const XIN* __restrict__ xin,
               const float* __restrict__ w_ih,
               const float* __restrict__ w_hh,
               const float* __restrict__ b_ih,
               const float* __restrict__ b_hh,
               float* __restrict__ hbuf,        // [2][64][512]
               XOUT* __restrict__ seqout,       // [64][1024][512] (WRITE_SEQ)
               int* __restrict__ barbase)       // 4 groups x 64 flag ints
{
  constexpr int D4 = D_IN / 4;
  constexpr bool XW_LDS = (D_IN <= 128);        // layer0: w_ih fits LDS
  constexpr int S4 = 128 + (XW_LDS ? D4 : 0);   // wv row stride (float4)
  constexpr int XC = D_IN / 8;                  // x K-chunk per kc
  constexpr int LD4 = (D_IN == 128) ? 5 : 7;

  extern __shared__ float lds[];
  float4* wv4 = (float4*)lds;                   // [RPW][S4] swizzled
  float4* hs4 = wv4 + RPW * S4;                 // [BPG][128] swizzled
  float4* xs4 = hs4 + BPG * 128;                // [BPG][D4]  swizzled
  float*  red = (float*)(xs4 + BPG * D4);       // [8][512]; row0 doubles as gbuf
  float*  bsum = red + 8 * 512;                 // [32]
  float*  cst  = bsum + RPW;                    // [16][8] c-state

  const int tid = threadIdx.x;
  const int bid = blockIdx.x;
  const int g   = bid & 3;
  const int w   = bid >> 2;
  const int b0g = g * BPG;
  const int u0  = w * UPW;
  int* bar = barbase + g * 64;                  // flags[w], monotone = step count

  // ---- weights -> LDS (XOR swizzle: col4 ^ ((r>>2)&7) spreads bank quads) ----
  for (int idx = tid; idx < RPW * S4; idx += NTH) {
    int r  = idx / S4;
    int c4 = idx - r * S4;
    int swz = (r >> 2) & 7;
    int grow = ((r >> 3) * HIDDEN) + u0 + (r & 7);
    if (c4 < 128) {
      float4 v = *(const float4*)(w_hh + (size_t)grow * HIDDEN + c4 * 4);
      wv4[r * S4 + (c4 ^ swz)] = v;
    } else {
      int c4x = c4 - 128;
      float4 v = *(const float4*)(w_ih + (size_t)grow * D_IN + c4x * 4);
      wv4[r * S4 + 128 + (c4x ^ swz)] = v;
    }
  }
  if (tid < RPW) {
    int grow = ((tid >> 3) * HIDDEN) + u0 + (tid & 7);
    bsum[tid] = b_ih[grow] + b_hh[grow];
  }
  if (tid < UPW * BPG) cst[tid] = 0.0f;

  const int rr = tid & 7;          // row quad
  const int bb = (tid >> 3) & 3;   // batch quad
  const int kc = tid >> 5;         // K chunk 0..7

  const float* wxg[4];             // layer1: x-weight rows stream from L2
  if (!XW_LDS) {
#pragma unroll
    for (int j = 0; j < 4; ++j) {
      int r = 4 * rr + j;
      int grow = ((r >> 3) * HIDDEN) + u0 + (r & 7);
      wxg[j] = w_ih + (size_t)grow * D_IN;
    }
  }
  __syncthreads();

  for (int t = 0; t < TSTEPS; ++t) {
    const float* hsrc = hbuf + (size_t)(t & 1) * (BATCH * HIDDEN);
    float*       hdst = hbuf + (size_t)((t + 1) & 1) * (BATCH * HIDDEN);

    // stage h_prev (16 batches x 512 floats) — coherent scalar loads,
    // scattered into the swizzled float4 LDS layout.
#pragma unroll
    for (int n = 0; n < (BPG * 512) / NTH; ++n) {   // 32 iters -> 32 in-flight
      int idx = tid + n * NTH;
      int b = idx >> 9, c = idx & 511;
      float v = ld_cc(hsrc + (size_t)(b0g + b) * HIDDEN + c);
      ((float*)hs4)[b * 512 + ((((c >> 2) ^ (b >> 2)) << 2) | (c & 3))] = v;
    }
    // stage x_t (read-only input / prev-kernel output: normal cached loads)
    for (int idx = tid; idx < BPG * D4; idx += NTH) {
      int b = idx >> LD4, c4 = idx & (D4 - 1);
      float4 v = Ld4<XIN>::go(xin + ((size_t)(b0g + b) * TSTEPS + t) * D_IN + c4 * 4);
      xs4[b * D4 + (c4 ^ (b >> 2))] = v;
    }
    __syncthreads();

    float acc[4][4];
#pragma unroll
    for (int j = 0; j < 4; ++j)
#pragma unroll
      for (int i = 0; i < 4; ++i) acc[j][i] = 0.0f;

    // ---- h part: K chunk [kc*64, kc*64+64) ----
#pragma unroll 4
    for (int kk = 0; kk < 16; ++kk) {
      const int k4 = kc * 16 + kk;
      float4 wq[4], hq[4];
#pragma unroll
      for (int j = 0; j < 4; ++j) wq[j] = wv4[(4 * rr + j) * S4 + (k4 ^ rr)];
#pragma unroll
      for (int i = 0; i < 4; ++i) hq[i] = hs4[(4 * bb + i) * 128 + (k4 ^ bb)];
#pragma unroll
      for (int j = 0; j < 4; ++j)
#pragma unroll
        for (int i = 0; i < 4; ++i) fma4(acc[j][i], wq[j], hq[i]);
    }
    // ---- x part ----
#pragma unroll 2
    for (int kk = 0; kk < XC / 4; ++kk) {
      const int k4 = kc * (XC / 4) + kk;
      float4 wq[4], xq[4];
      if constexpr (XW_LDS) {
#pragma unroll
        for (int j = 0; j < 4; ++j) wq[j] = wv4[(4 * rr + j) * S4 + 128 + (k4 ^ rr)];
      } else {
#pragma unroll
        for (int j = 0; j < 4; ++j) wq[j] = *(const float4*)(wxg[j] + k4 * 4);
      }
#pragma unroll
      for (int i = 0; i < 4; ++i) xq[i] = xs4[(4 * bb + i) * D4 + (k4 ^ bb)];
#pragma unroll
      for (int j = 0; j < 4; ++j)
#pragma unroll
        for (int i = 0; i < 4; ++i) fma4(acc[j][i], wq[j], xq[i]);
    }

    // ---- K-split reduction ----
#pragma unroll
    for (int j = 0; j < 4; ++j)
#pragma unroll
      for (int i = 0; i < 4; ++i)
        red[kc * 512 + (4 * rr + j) * 16 + 4 * bb + i] = acc[j][i];
    __syncthreads();
    {
      const int a0 = tid, a1 = tid + 256;
      float s0 = bsum[a0 >> 4], s1 = bsum[a1 >> 4];
#pragma unroll
      for (int k2 = 0; k2 < 8; ++k2) {
        s0 += red[k2 * 512 + a0];
        s1 += red[k2 * 512 + a1];
      }
      red[a0] = s0;   // gbuf alias: only this thread reads/writes column a0/a1
      red[a1] = s1;
    }
    __syncthreads();

    // ---- gates / state update ----
    if (tid < UPW * BPG) {
      const int lu = tid & 7, bl = tid >> 3;
      float gi = red[(0  + lu) * 16 + bl];
      float gf = red[(8  + lu) * 16 + bl];
      float gg = red[(16 + lu) * 16 + bl];
      float go = red[(24 + lu) * 16 + bl];
      float iv = sigm(gi), fv = sigm(gf), gv = tanh_fast(gg), ov = sigm(go);
      float c = fv * cst[tid] + iv * gv;
      cst[tid] = c;
      float hn = ov * tanh_fast(c);
      const int b = b0g + bl, u = u0 + lu;
      st_cc(hdst + (size_t)b * HIDDEN + u, hn);       // coherent write-through
      if constexpr (WRITE_SEQ)
        seqout[((size_t)b * TSTEPS + t) * HIDDEN + u] = to_xout<XOUT>(hn);
    }

    // ---- group barrier: flag array, relaxed agent atomics, no fences ----
    // __syncthreads drains each wave's vmcnt (compiler-emitted s_waitcnt
    // vmcnt(0) before s_barrier), so all h stores are globally visible
    // before tid0 publishes the flag. Bounded spin: see SPIN_LIMIT.
    __syncthreads();
    if (tid == 0)
      __hip_atomic_store(&bar[w], t + 1, __ATOMIC_RELAXED, __HIP_MEMORY_SCOPE_AGENT);
    if (tid < WPG) {   // wave 0 polls all 64 flags; monotone values, no reset
      unsigned long long spin0 = __builtin_amdgcn_s_memrealtime();
      while (true) {
        int v = __hip_atomic_load(&bar[tid], __ATOMIC_RELAXED, __HIP_MEMORY_SCOPE_AGENT);
        if (__all(v >= t + 1)) break;
        if (__builtin_amdgcn_s_memrealtime() - spin0 > SPIN_LIMIT) break;  // bail: fail, don't hang
        __builtin_amdgcn_s_sleep(2);
      }
    }
    __syncthreads();
  }
}

// ---------------------------------------------------------------------------
// FC: out[b][o] = dot(h2[b], fc_w[o]) + fc_b[o].  grid 8, block 256.
// ---------------------------------------------------------------------------
__global__ __launch_bounds__(NTH, 1)
void fc_kernel(const float* __restrict__ h2, const float* __restrict__ fcw,
               const float* __restrict__ fcb, float* __restrict__ out)
{
  extern __shared__ float lds[];
  float4* fw4 = (float4*)lds;          // [64][128] swizzled
  float4* h24 = fw4 + 64 * 128;        // [8][128]
  const int tid = threadIdx.x;
  const int bq  = blockIdx.x;

  for (int idx = tid; idx < 64 * 128; idx += NTH) {
    int o = idx >> 7, c4 = idx & 127;
    fw4[o * 128 + (c4 ^ (o & 7))] = *(const float4*)(fcw + (size_t)o * HIDDEN + c4 * 4);
  }
  for (int idx = tid; idx < 8 * 128; idx += NTH) {
    int b = idx >> 7, c4 = idx & 127;
    h24[b * 128 + c4] = *(const float4*)(h2 + (size_t)(bq * 8 + b) * HIDDEN + c4 * 4);
  }
  __syncthreads();

  const int o = tid & 63, bs = tid >> 6;
  float a0 = 0.f, a1 = 0.f;
  for (int c4 = 0; c4 < 128; ++c4) {
    float4 wv = fw4[o * 128 + (c4 ^ (o & 7))];
    float4 h0 = h24[(2 * bs) * 128 + c4];
    float4 h1 = h24[(2 * bs + 1) * 128 + c4];
    fma4(a0, wv, h0);
    fma4(a1, wv, h1);
  }
  const float bo = fcb[o];
  out[(size_t)(bq * 8 + 2 * bs) * 64 + o]     = a0 + bo;
  out[(size_t)(bq * 8 + 2 * bs + 1) * 64 + o] = a1 + bo;
}

__global__ void init_ws(float* hbuf0, float* hbuf1, int* bars)
{
  int i = blockIdx.x * blockDim.x + threadIdx.x;
  if (i < 2 * BATCH * HIDDEN) { hbuf0[i] = 0.f; hbuf1[i] = 0.f; }
  if (i < 512) bars[i] = 0;
}

// ---------------------------------------------------------------------------
extern "C" void kernel_launch(void* const* d_in, const int* in_sizes, int n_in,
                              void* d_out, int out_size, void* d_ws, size_t ws_size,
                              hipStream_t stream)
{
  const float* x    = (const float*)d_in[0];
  const float* wih0 = (const float*)d_in[1];
  const float* whh0 = (const float*)d_in[2];
  const float* bih0 = (const float*)d_in[3];
  const float* bhh0 = (const float*)d_in[4];
  const float* wih1 = (const float*)d_in[5];
  const float* whh1 = (const float*)d_in[6];
  const float* bih1 = (const float*)d_in[7];
  const float* bhh1 = (const float*)d_in[8];
  const float* fcw  = (const float*)d_in[9];
  const float* fcb  = (const float*)d_in[10];
  float* out = (float*)d_out;

  float* wsf   = (float*)d_ws;
  int*   bars  = (int*)d_ws;                 // 512 ints (L0: 0..255, L1: 256..511)
  float* hbuf0 = wsf + 512;
  float* hbuf1 = hbuf0 + 2 * BATCH * HIDDEN;
  float* seqf  = hbuf1 + 2 * BATCH * HIDDEN;
  const size_t seq_elems = (size_t)BATCH * TSTEPS * HIDDEN;
  const size_t base_bytes = (512 + 4 * BATCH * HIDDEN) * 4;
  const bool f32seq = ws_size >= base_bytes + seq_elems * 4;

  // LDS sizes (bytes)
  const size_t lds0  = (size_t)((RPW * 160 + BPG * 128 + BPG * 32) * 4 + 8 * 512 + RPW + 128) * 4;
  const size_t lds1  = (size_t)((RPW * 128 + BPG * 128 + BPG * 128) * 4 + 8 * 512 + RPW + 128) * 4;
  const size_t ldsfc = (size_t)(64 * 128 + 8 * 128) * 16;

  hipLaunchKernelGGL(init_ws, dim3(256), dim3(256), 0, stream, hbuf0, hbuf1, bars);

  int* bar0 = bars;
  int* bar1 = bars + 256;
  float* dummy = nullptr;

  if (f32seq) {
    auto* k0 = lstm_scan<128, true,  float, float>;
    auto* k1 = lstm_scan<512, false, float, float>;
    hipFuncSetAttribute((const void*)k0, hipFuncAttributeMaxDynamicSharedMemorySize, (int)lds0);
    hipFuncSetAttribute((const void*)k1, hipFuncAttributeMaxDynamicSharedMemorySize, (int)lds1);
    float* seqp = seqf;
    void* a0[] = { (void*)&x,    (void*)&wih0, (void*)&whh0, (void*)&bih0, (void*)&bhh0,
                   (void*)&hbuf0, (void*)&seqp, (void*)&bar0 };
    if (hipLaunchCooperativeKernel((const void*)k0, dim3(NGRP * WPG), dim3(NTH), a0,
                                   (unsigned)lds0, stream) != hipSuccess) {
      lstm_scan<128, true, float, float><<<dim3(NGRP * WPG), dim3(NTH), lds0, stream>>>(
          x, wih0, whh0, bih0, bhh0, hbuf0, seqp, bar0);
    }
    const float* seqc = seqf;
    void* a1[] = { (void*)&seqc, (void*)&wih1, (void*)&whh1, (void*)&bih1, (void*)&bhh1,
                   (void*)&hbuf1, (void*)&dummy, (void*)&bar1 };
    if (hipLaunchCooperativeKernel((const void*)k1, dim3(NGRP * WPG), dim3(NTH), a1,
                                   (unsigned)lds1, stream) != hipSuccess) {
      lstm_scan<512, false, float, float><<<dim3(NGRP * WPG), dim3(NTH), lds1, stream>>>(
          seqc, wih1, whh1, bih1, bhh1, hbuf1, dummy, bar1);
    }
  } else {
    auto* k0 = lstm_scan<128, true,  float, bf16>;
    auto* k1 = lstm_scan<512, false, bf16, float>;
    hipFuncSetAttribute((const void*)k0, hipFuncAttributeMaxDynamicSharedMemorySize, (int)lds0);
    hipFuncSetAttribute((const void*)k1, hipFuncAttributeMaxDynamicSharedMemorySize, (int)lds1);
    bf16* seqb = (bf16*)seqf;
    void* a0[] = { (void*)&x,    (void*)&wih0, (void*)&whh0, (void*)&bih0, (void*)&bhh0,
                   (void*)&hbuf0, (void*)&seqb, (void*)&bar0 };
    if (hipLaunchCooperativeKernel((const void*)k0, dim3(NGRP * WPG), dim3(NTH), a0,
                                   (unsigned)lds0, stream) != hipSuccess) {
      lstm_scan<128, true, float, bf16><<<dim3(NGRP * WPG), dim3(NTH), lds0, stream>>>(
          x, wih0, whh0, bih0, bhh0, hbuf0, seqb, bar0);
    }
    const bf16* seqc = (const bf16*)seqf;
    void* a1[] = { (void*)&seqc, (void*)&wih1, (void*)&whh1, (void*)&bih1, (void*)&bhh1,
                   (void*)&hbuf1, (void*)&dummy, (void*)&bar1 };
    if (hipLaunchCooperativeKernel((const void*)k1, dim3(NGRP * WPG), dim3(NTH), a1,
                                   (unsigned)lds1, stream) != hipSuccess) {
      lstm_scan<512, false, bf16, float><<<dim3(NGRP * WPG), dim3(NTH), lds1, stream>>>(
          seqc, wih1, whh1, bih1, bhh1, hbuf1, dummy, bar1);
    }
  }

  hipFuncSetAttribute((const void*)fc_kernel, hipFuncAttributeMaxDynamicSharedMemorySize, (int)ldsfc);
  hipLaunchKernelGGL(fc_kernel, dim3(8), dim3(NTH), ldsfc, stream, hbuf1, fcw, fcb, out);
}

// Round 5
// 19514.909 us; speedup vs baseline: 4.2804x; 1.9106x over previous
//
#include <hip/hip_runtime.h>
#include <hip/hip_bf16.h>

// LSTM_19267223290530 — 2-layer LSTM (B=64,T=1024,IN=128,HID=512) + FC.
// Round 5: shorten the per-step serial latency chain.
//  (a) epoch-wait moved to TOP of step; x[t] prefetched into regs before it.
//  (b) h coherent loads ISSUED into regs, x-part computed while they fly,
//      h written to LDS only before the h-part (latency hidden under x-part).
//  (c) poll topology: arrival flags (stores) -> wg0 polls flags -> wg0
//      publishes single epoch word -> all wgs poll ONE address (broadcast).
//  All sync ops remain relaxed agent-scope (no L2 writeback/invalidate).

#define NTH 256
#define WPG 64      // workgroups per barrier group
#define NGRP 4      // batch groups
#define BPG 16      // batches per group
#define UPW 8       // hidden units per wg
#define RPW 32      // gate rows per wg (4*UPW)
#define HIDDEN 512
#define TSTEPS 1024
#define BATCH 64

// spin bail-out: ~4 s in s_memrealtime ticks. Fires only if co-residency /
// coherence assumptions break; we then fail visibly instead of hanging.
#define SPIN_LIMIT 400000000ull

using bf16 = __hip_bfloat16;

__device__ __forceinline__ float b2fl(unsigned short s) {
  return __uint_as_float(((unsigned int)s) << 16);
}

template<typename T> struct Ld4;
template<> struct Ld4<float> {
  static __device__ __forceinline__ float4 go(const float* p) { return *(const float4*)p; }
};
template<> struct Ld4<bf16> {
  static __device__ __forceinline__ float4 go(const bf16* p) {
    ushort4 v = *(const ushort4*)p;
    return make_float4(b2fl(v.x), b2fl(v.y), b2fl(v.z), b2fl(v.w));
  }
};

template<typename T> __device__ __forceinline__ T to_xout(float f);
template<> __device__ __forceinline__ float to_xout<float>(float f) { return f; }
template<> __device__ __forceinline__ bf16 to_xout<bf16>(float f) { return __float2bfloat16(f); }

__device__ __forceinline__ float sigm(float x) { return 1.0f / (1.0f + __expf(-x)); }
__device__ __forceinline__ float tanh_fast(float x) {
  float ax = fabsf(x);
  float e2 = __expf(2.0f * ax);
  float t  = 1.0f - 2.0f / (e2 + 1.0f);
  return copysignf(t, x);
}
__device__ __forceinline__ void fma4(float& a, const float4 w, const float4 h) {
  a = fmaf(w.x, h.x, a);
  a = fmaf(w.y, h.y, a);
  a = fmaf(w.z, h.z, a);
  a = fmaf(w.w, h.w, a);
}

// coherent (device-visible, no cache maintenance) scalar ops
__device__ __forceinline__ void st_cc(float* p, float v) {
  __hip_atomic_store(p, v, __ATOMIC_RELAXED, __HIP_MEMORY_SCOPE_AGENT);
}
__device__ __forceinline__ float ld_cc(const float* p) {
  return __hip_atomic_load((float*)p, __ATOMIC_RELAXED, __HIP_MEMORY_SCOPE_AGENT);
}
__device__ __forceinline__ void cfence() { asm volatile("" ::: "memory"); }

// ---------------------------------------------------------------------------
// Persistent LSTM scan. grid = 256 wgs x 256 thr, 1 wg/CU, all co-resident.
// group g = bid&3 owns batches [16g,16g+16); wg w = bid>>2 owns units [8w,8w+8).
// Barrier state per layer (512 ints): flags[g*64 + w] monotone step count;
// epoch word per group at 320 + g*16.
// ---------------------------------------------------------------------------
template<int D_IN, bool WRITE_SEQ, typename XIN, typename XOUT>
__global__ __launch_bounds__(NTH, 1)
void lstm_scan(const XIN* __restrict__ xin,
               const float* __restrict__ w_ih,
               const float* __restrict__ w_hh,
               const float* __restrict__ b_ih,
               const float* __restrict__ b_hh,
               float* __restrict__ hbuf,        // [2][64][512]
               XOUT* __restrict__ seqout,       // [64][1024][512] (WRITE_SEQ)
               int* __restrict__ barbase)       // 512 ints for this layer
{
  constexpr int D4 = D_IN / 4;
  constexpr bool XW_LDS = (D_IN <= 128);        // layer0: w_ih fits LDS
  constexpr int S4 = 128 + (XW_LDS ? D4 : 0);   // wv row stride (float4)
  constexpr int XC = D_IN / 8;                  // x K-chunk per kc
  constexpr int LD4 = (D_IN == 128) ? 5 : 7;
  constexpr int XPT = (BPG * D4) / NTH;         // x float4 per thread (L0:2, L1:8)
  constexpr int HPT = (BPG * HIDDEN) / NTH;     // h floats per thread (32)

  extern __shared__ float lds[];
  float4* wv4 = (float4*)lds;                   // [RPW][S4] swizzled
  float4* hs4 = wv4 + RPW * S4;                 // [BPG][128] swizzled
  float4* xs4 = hs4 + BPG * 128;                // [BPG][D4]  swizzled
  float*  red = (float*)(xs4 + BPG * D4);       // [8][512]; row0 doubles as gbuf
  float*  bsum = red + 8 * 512;                 // [32]
  float*  cst  = bsum + RPW;                    // [16][8] c-state

  const int tid = threadIdx.x;
  const int bid = blockIdx.x;
  const int g   = bid & 3;
  const int w   = bid >> 2;
  const int b0g = g * BPG;
  const int u0  = w * UPW;
  int* flags = barbase + g * 64;                // arrival flags, monotone
  int* epoch = barbase + 320 + g * 16;          // single release word per group

  // ---- weights -> LDS (XOR swizzle: col4 ^ ((r>>2)&7) spreads bank quads) ----
  for (int idx = tid; idx < RPW * S4; idx += NTH) {
    int r  = idx / S4;
    int c4 = idx - r * S4;
    int swz = (r >> 2) & 7;
    int grow = ((r >> 3) * HIDDEN) + u0 + (r & 7);
    if (c4 < 128) {
      float4 v = *(const float4*)(w_hh + (size_t)grow * HIDDEN + c4 * 4);
      wv4[r * S4 + (c4 ^ swz)] = v;
    } else {
      int c4x = c4 - 128;
      float4 v = *(const float4*)(w_ih + (size_t)grow * D_IN + c4x * 4);
      wv4[r * S4 + 128 + (c4x ^ swz)] = v;
    }
  }
  if (tid < RPW) {
    int grow = ((tid >> 3) * HIDDEN) + u0 + (tid & 7);
    bsum[tid] = b_ih[grow] + b_hh[grow];
  }
  if (tid < UPW * BPG) cst[tid] = 0.0f;

  const int rr = tid & 7;          // row quad
  const int bb = (tid >> 3) & 3;   // batch quad
  const int kc = tid >> 5;         // K chunk 0..7

  const float* wxg[4];             // layer1: x-weight rows stream from L2
  if (!XW_LDS) {
#pragma unroll
    for (int j = 0; j < 4; ++j) {
      int r = 4 * rr + j;
      int grow = ((r >> 3) * HIDDEN) + u0 + (r & 7);
      wxg[j] = w_ih + (size_t)grow * D_IN;
    }
  }
  __syncthreads();

  for (int t = 0; t < TSTEPS; ++t) {
    const float* hsrc = hbuf + (size_t)(t & 1) * (BATCH * HIDDEN);
    float*       hdst = hbuf + (size_t)((t + 1) & 1) * (BATCH * HIDDEN);

    // ---- x[t] prefetch into regs (cached; independent of the barrier) ----
    float4 xr[XPT];
#pragma unroll
    for (int n = 0; n < XPT; ++n) {
      int idx = tid + n * NTH;
      int b = idx >> LD4, c4 = idx & (D4 - 1);
      xr[n] = Ld4<XIN>::go(xin + ((size_t)(b0g + b) * TSTEPS + t) * D_IN + c4 * 4);
    }

    // ---- wait for h(t-1): poll ONE epoch word (same addr -> broadcast) ----
    if (t > 0) {
      unsigned long long sp0 = __builtin_amdgcn_s_memrealtime();
      while (__hip_atomic_load(epoch, __ATOMIC_RELAXED, __HIP_MEMORY_SCOPE_AGENT) < t) {
        if (__builtin_amdgcn_s_memrealtime() - sp0 > SPIN_LIMIT) break;  // fail, don't hang
        __builtin_amdgcn_s_sleep(1);
      }
      cfence();   // forbid hoisting the h loads above the poll
    }

    // ---- issue coherent h loads into regs (latency hides under x-part) ----
    float hr[HPT];
#pragma unroll
    for (int n = 0; n < HPT; ++n) {
      int idx = tid + n * NTH;
      int b = idx >> 9, c = idx & 511;
      hr[n] = ld_cc(hsrc + (size_t)(b0g + b) * HIDDEN + c);
    }

    // ---- x regs -> LDS (swizzled) ----
#pragma unroll
    for (int n = 0; n < XPT; ++n) {
      int idx = tid + n * NTH;
      int b = idx >> LD4, c4 = idx & (D4 - 1);
      xs4[b * D4 + (c4 ^ (b >> 2))] = xr[n];
    }
    __syncthreads();   // xs4 ready (hs4 not yet)

    float acc[4][4];
#pragma unroll
    for (int j = 0; j < 4; ++j)
#pragma unroll
      for (int i = 0; i < 4; ++i) acc[j][i] = 0.0f;

    // ---- X-PART first (only xs4 + weights; h loads still in flight) ----
#pragma unroll 2
    for (int kk = 0; kk < XC / 4; ++kk) {
      const int k4 = kc * (XC / 4) + kk;
      float4 wq[4], xq[4];
      if constexpr (XW_LDS) {
#pragma unroll
        for (int j = 0; j < 4; ++j) wq[j] = wv4[(4 * rr + j) * S4 + 128 + (k4 ^ rr)];
      } else {
#pragma unroll
        for (int j = 0; j < 4; ++j) wq[j] = *(const float4*)(wxg[j] + k4 * 4);
      }
#pragma unroll
      for (int i = 0; i < 4; ++i) xq[i] = xs4[(4 * bb + i) * D4 + (k4 ^ bb)];
#pragma unroll
      for (int j = 0; j < 4; ++j)
#pragma unroll
        for (int i = 0; i < 4; ++i) fma4(acc[j][i], wq[j], xq[i]);
    }

    // ---- h regs -> LDS (compiler inserts the vmcnt wait right here) ----
#pragma unroll
    for (int n = 0; n < HPT; ++n) {
      int idx = tid + n * NTH;
      int b = idx >> 9, c = idx & 511;
      ((float*)hs4)[b * 512 + ((((c >> 2) ^ (b >> 2)) << 2) | (c & 3))] = hr[n];
    }
    __syncthreads();   // hs4 ready

    // ---- H-PART: K chunk [kc*64, kc*64+64) ----
#pragma unroll 4
    for (int kk = 0; kk < 16; ++kk) {
      const int k4 = kc * 16 + kk;
      float4 wq[4], hq[4];
#pragma unroll
      for (int j = 0; j < 4; ++j) wq[j] = wv4[(4 * rr + j) * S4 + (k4 ^ rr)];
#pragma unroll
      for (int i = 0; i < 4; ++i) hq[i] = hs4[(4 * bb + i) * 128 + (k4 ^ bb)];
#pragma unroll
      for (int j = 0; j < 4; ++j)
#pragma unroll
        for (int i = 0; i < 4; ++i) fma4(acc[j][i], wq[j], hq[i]);
    }

    // ---- K-split reduction ----
#pragma unroll
    for (int j = 0; j < 4; ++j)
#pragma unroll
      for (int i = 0; i < 4; ++i)
        red[kc * 512 + (4 * rr + j) * 16 + 4 * bb + i] = acc[j][i];
    __syncthreads();
    {
      const int a0 = tid, a1 = tid + 256;
      float s0 = bsum[a0 >> 4], s1 = bsum[a1 >> 4];
#pragma unroll
      for (int k2 = 0; k2 < 8; ++k2) {
        s0 += red[k2 * 512 + a0];
        s1 += red[k2 * 512 + a1];
      }
      red[a0] = s0;   // gbuf alias: only this thread reads/writes column a0/a1
      red[a1] = s1;
    }
    __syncthreads();

    // ---- gates / state update ----
    if (tid < UPW * BPG) {
      const int lu = tid & 7, bl = tid >> 3;
      float gi = red[(0  + lu) * 16 + bl];
      float gf = red[(8  + lu) * 16 + bl];
      float gg = red[(16 + lu) * 16 + bl];
      float go = red[(24 + lu) * 16 + bl];
      float iv = sigm(gi), fv = sigm(gf), gv = tanh_fast(gg), ov = sigm(go);
      float c = fv * cst[tid] + iv * gv;
      cst[tid] = c;
      float hn = ov * tanh_fast(c);
      const int b = b0g + bl, u = u0 + lu;
      st_cc(hdst + (size_t)b * HIDDEN + u, hn);       // coherent write-through
      if constexpr (WRITE_SEQ)
        seqout[((size_t)b * TSTEPS + t) * HIDDEN + u] = to_xout<XOUT>(hn);
    }

    // ---- arrival + release ----
    // __syncthreads drains each wave's vmcnt (compiler emits s_waitcnt
    // vmcnt(0) before s_barrier), so all h stores are device-visible
    // before the flag store below.
    __syncthreads();
    if (tid == 0) {
      __hip_atomic_store(&flags[w], t + 1, __ATOMIC_RELAXED, __HIP_MEMORY_SCOPE_AGENT);
    }
    cfence();   // keep flag store ordered before wg0's flag polling
    if (w == 0 && tid < WPG) {   // wg0 wave0: gather arrivals, publish epoch
      unsigned long long sp0 = __builtin_amdgcn_s_memrealtime();
      while (true) {
        int v = __hip_atomic_load(&flags[tid], __ATOMIC_RELAXED, __HIP_MEMORY_SCOPE_AGENT);
        if (__all(v >= t + 1)) break;
        if (__builtin_amdgcn_s_memrealtime() - sp0 > SPIN_LIMIT) break;  // fail, don't hang
        __builtin_amdgcn_s_sleep(1);
      }
      if (tid == 0)
        __hip_atomic_store(epoch, t + 1, __ATOMIC_RELAXED, __HIP_MEMORY_SCOPE_AGENT);
    }
    // no trailing __syncthreads: waves proceed to t+1 prefetch; LDS reuse is
    // safe because the pre-flag __syncthreads is after all LDS reads of step t.
  }
}

// ---------------------------------------------------------------------------
// FC: out[b][o] = dot(h2[b], fc_w[o]) + fc_b[o].  grid 8, block 256.
// ---------------------------------------------------------------------------
__global__ __launch_bounds__(NTH, 1)
void fc_kernel(const float* __restrict__ h2, const float* __restrict__ fcw,
               const float* __restrict__ fcb, float* __restrict__ out)
{
  extern __shared__ float lds[];
  float4* fw4 = (float4*)lds;          // [64][128] swizzled
  float4* h24 = fw4 + 64 * 128;        // [8][128]
  const int tid = threadIdx.x;
  const int bq  = blockIdx.x;

  for (int idx = tid; idx < 64 * 128; idx += NTH) {
    int o = idx >> 7, c4 = idx & 127;
    fw4[o * 128 + (c4 ^ (o & 7))] = *(const float4*)(fcw + (size_t)o * HIDDEN + c4 * 4);
  }
  for (int idx = tid; idx < 8 * 128; idx += NTH) {
    int b = idx >> 7, c4 = idx & 127;
    h24[b * 128 + c4] = *(const float4*)(h2 + (size_t)(bq * 8 + b) * HIDDEN + c4 * 4);
  }
  __syncthreads();

  const int o = tid & 63, bs = tid >> 6;
  float a0 = 0.f, a1 = 0.f;
  for (int c4 = 0; c4 < 128; ++c4) {
    float4 wv = fw4[o * 128 + (c4 ^ (o & 7))];
    float4 h0 = h24[(2 * bs) * 128 + c4];
    float4 h1 = h24[(2 * bs + 1) * 128 + c4];
    fma4(a0, wv, h0);
    fma4(a1, wv, h1);
  }
  const float bo = fcb[o];
  out[(size_t)(bq * 8 + 2 * bs) * 64 + o]     = a0 + bo;
  out[(size_t)(bq * 8 + 2 * bs + 1) * 64 + o] = a1 + bo;
}

__global__ void init_ws(float* hbuf0, float* hbuf1, int* bars)
{
  int i = blockIdx.x * blockDim.x + threadIdx.x;
  if (i < 2 * BATCH * HIDDEN) { hbuf0[i] = 0.f; hbuf1[i] = 0.f; }
  if (i < 1024) bars[i] = 0;
}

// ---------------------------------------------------------------------------
extern "C" void kernel_launch(void* const* d_in, const int* in_sizes, int n_in,
                              void* d_out, int out_size, void* d_ws, size_t ws_size,
                              hipStream_t stream)
{
  const float* x    = (const float*)d_in[0];
  const float* wih0 = (const float*)d_in[1];
  const float* whh0 = (const float*)d_in[2];
  const float* bih0 = (const float*)d_in[3];
  const float* bhh0 = (const float*)d_in[4];
  const float* wih1 = (const float*)d_in[5];
  const float* whh1 = (const float*)d_in[6];
  const float* bih1 = (const float*)d_in[7];
  const float* bhh1 = (const float*)d_in[8];
  const float* fcw  = (const float*)d_in[9];
  const float* fcb  = (const float*)d_in[10];
  float* out = (float*)d_out;

  float* wsf   = (float*)d_ws;
  int*   bars  = (int*)d_ws;                 // 1024 ints: L0 [0..511], L1 [512..1023]
  float* hbuf0 = wsf + 1024;
  float* hbuf1 = hbuf0 + 2 * BATCH * HIDDEN;
  float* seqf  = hbuf1 + 2 * BATCH * HIDDEN;
  const size_t seq_elems = (size_t)BATCH * TSTEPS * HIDDEN;
  const size_t base_bytes = (1024 + 4 * BATCH * HIDDEN) * 4;
  const bool f32seq = ws_size >= base_bytes + seq_elems * 4;

  // LDS sizes (bytes)
  const size_t lds0  = (size_t)((RPW * 160 + BPG * 128 + BPG * 32) * 4 + 8 * 512 + RPW + 128) * 4;
  const size_t lds1  = (size_t)((RPW * 128 + BPG * 128 + BPG * 128) * 4 + 8 * 512 + RPW + 128) * 4;
  const size_t ldsfc = (size_t)(64 * 128 + 8 * 128) * 16;

  hipLaunchKernelGGL(init_ws, dim3(256), dim3(256), 0, stream, hbuf0, hbuf1, bars);

  int* bar0 = bars;
  int* bar1 = bars + 512;
  float* dummy = nullptr;

  if (f32seq) {
    auto* k0 = lstm_scan<128, true,  float, float>;
    auto* k1 = lstm_scan<512, false, float, float>;
    hipFuncSetAttribute((const void*)k0, hipFuncAttributeMaxDynamicSharedMemorySize, (int)lds0);
    hipFuncSetAttribute((const void*)k1, hipFuncAttributeMaxDynamicSharedMemorySize, (int)lds1);
    float* seqp = seqf;
    void* a0[] = { (void*)&x,    (void*)&wih0, (void*)&whh0, (void*)&bih0, (void*)&bhh0,
                   (void*)&hbuf0, (void*)&seqp, (void*)&bar0 };
    if (hipLaunchCooperativeKernel((const void*)k0, dim3(NGRP * WPG), dim3(NTH), a0,
                                   (unsigned)lds0, stream) != hipSuccess) {
      lstm_scan<128, true, float, float><<<dim3(NGRP * WPG), dim3(NTH), lds0, stream>>>(
          x, wih0, whh0, bih0, bhh0, hbuf0, seqp, bar0);
    }
    const float* seqc = seqf;
    void* a1[] = { (void*)&seqc, (void*)&wih1, (void*)&whh1, (void*)&bih1, (void*)&bhh1,
                   (void*)&hbuf1, (void*)&dummy, (void*)&bar1 };
    if (hipLaunchCooperativeKernel((const void*)k1, dim3(NGRP * WPG), dim3(NTH), a1,
                                   (unsigned)lds1, stream) != hipSuccess) {
      lstm_scan<512, false, float, float><<<dim3(NGRP * WPG), dim3(NTH), lds1, stream>>>(
          seqc, wih1, whh1, bih1, bhh1, hbuf1, dummy, bar1);
    }
  } else {
    auto* k0 = lstm_scan<128, true,  float, bf16>;
    auto* k1 = lstm_scan<512, false, bf16, float>;
    hipFuncSetAttribute((const void*)k0, hipFuncAttributeMaxDynamicSharedMemorySize, (int)lds0);
    hipFuncSetAttribute((const void*)k1, hipFuncAttributeMaxDynamicSharedMemorySize, (int)lds1);
    bf16* seqb = (bf16*)seqf;
    void* a0[] = { (void*)&x,    (void*)&wih0, (void*)&whh0, (void*)&bih0, (void*)&bhh0,
                   (void*)&hbuf0, (void*)&seqb, (void*)&bar0 };
    if (hipLaunchCooperativeKernel((const void*)k0, dim3(NGRP * WPG), dim3(NTH), a0,
                                   (unsigned)lds0, stream) != hipSuccess) {
      lstm_scan<128, true, float, bf16><<<dim3(NGRP * WPG), dim3(NTH), lds0, stream>>>(
          x, wih0, whh0, bih0, bhh0, hbuf0, seqb, bar0);
    }
    const bf16* seqc = (const bf16*)seqf;
    void* a1[] = { (void*)&seqc, (void*)&wih1, (void*)&whh1, (void*)&bih1, (void*)&bhh1,
                   (void*)&hbuf1, (void*)&dummy, (void*)&bar1 };
    if (hipLaunchCooperativeKernel((const void*)k1, dim3(NGRP * WPG), dim3(NTH), a1,
                                   (unsigned)lds1, stream) != hipSuccess) {
      lstm_scan<512, false, bf16, float><<<dim3(NGRP * WPG), dim3(NTH), lds1, stream>>>(
          seqc, wih1, whh1, bih1, bhh1, hbuf1, dummy, bar1);
    }
  }

  hipFuncSetAttribute((const void*)fc_kernel, hipFuncAttributeMaxDynamicSharedMemorySize, (int)ldsfc);
  hipLaunchKernelGGL(fc_kernel, dim3(8), dim3(NTH), ldsfc, stream, hbuf1, fcw, fcb, out);
}